// Round 8
// baseline (8456.820 us; speedup 1.0000x reference)
//
#include <hip/hip_runtime.h>
#include <hip/hip_bf16.h>
#include <stdint.h>

// Problem constants (fixed by the reference): T=512, B=64, IN=H=1024, L=2
#define TT 512
#define BB 64
#define HH 1024
#define BH 65536    // B*H elements
#define KD 2048     // IN+H == H+H

typedef __attribute__((ext_vector_type(8))) short short8;
typedef __attribute__((ext_vector_type(4))) float f32x4;

__device__ __forceinline__ unsigned short f2bf(float f) {
  union { float f; unsigned int u; } v; v.f = f;
  unsigned int r = v.u + 0x7fffu + ((v.u >> 16) & 1u);  // RNE
  return (unsigned short)(r >> 16);
}
__device__ __forceinline__ float fsig(float x)  { return 1.0f / (1.0f + __expf(-x)); }
__device__ __forceinline__ float ftanhf(float x){ return 1.0f - 2.0f / (__expf(2.0f * x) + 1.0f); }

// ---------------- x -> bf16 ----------------
__global__ void cvt_x_kernel(const float* __restrict__ x, unsigned short* __restrict__ xbf) {
  const int n4 = (TT * BB * 1024) / 4;
  int stride = gridDim.x * blockDim.x;
  for (int i = blockIdx.x * blockDim.x + threadIdx.x; i < n4; i += stride) {
    float4 v = ((const float4*)x)[i];
    unsigned long long p = (unsigned long long)f2bf(v.x)
        | ((unsigned long long)f2bf(v.y) << 16)
        | ((unsigned long long)f2bf(v.z) << 32)
        | ((unsigned long long)f2bf(v.w) << 48);
    ((unsigned long long*)xbf)[i] = p;
  }
}

// ---------------- W [4096][2048] f32 -> bf16, LDS-image layout ----------------
// Ws[g][kk 0..63][nrow 0..31][hi 0..3][8 bf16]  (16B chunks; 128 KB per slice g)
// nrow: nt=nrow>>4, q=(nrow>>2)&3, jl=nrow&3 -> W row = q*1024 + g*8 + nt*4 + jl
// kk<32: k = kk*32 + hi*8 (x-half); kk>=32: k = 1024 + (kk-32)*32 + hi*8 (h-half)
__global__ void cvt_w_kernel(const float* __restrict__ W, unsigned short* __restrict__ Ws) {
  int idx = blockIdx.x * blockDim.x + threadIdx.x;   // < 128*64*32*4 = 1,048,576
  int hi = idx & 3;
  int nr = (idx >> 2) & 31;
  int kk = (idx >> 7) & 63;
  int g  = idx >> 13;
  int q  = (nr >> 2) & 3;
  int nt = nr >> 4;
  int jl = nr & 3;
  int grow = (q << 10) + (g << 3) + (nt << 2) + jl;
  int k = ((kk < 32) ? (kk << 5) : (1024 + ((kk - 32) << 5))) + (hi << 3);
  const float* src = W + (size_t)grow * KD + k;
  float4 v0 = ((const float4*)src)[0];
  float4 v1 = ((const float4*)src)[1];
  unsigned long long p0 = (unsigned long long)f2bf(v0.x)
      | ((unsigned long long)f2bf(v0.y) << 16)
      | ((unsigned long long)f2bf(v0.z) << 32)
      | ((unsigned long long)f2bf(v0.w) << 48);
  unsigned long long p1 = (unsigned long long)f2bf(v1.x)
      | ((unsigned long long)f2bf(v1.y) << 16)
      | ((unsigned long long)f2bf(v1.z) << 32)
      | ((unsigned long long)f2bf(v1.w) << 48);
  unsigned long long* dst = (unsigned long long*)(Ws + ((size_t)g << 16) + (kk << 10) + (nr << 5) + (hi << 3));
  dst[0] = p0;
  dst[1] = p1;
}

// ---------------- initial h -> hist slot 0 ----------------
__global__ void init_state_kernel(const float* __restrict__ h0in,
                                  unsigned short* h0s0, unsigned short* h1s0) {
  int i = blockIdx.x * blockDim.x + threadIdx.x;  // < BH
  h0s0[i] = f2bf(h0in[i]);
  h1s0[i] = f2bf(h0in[BH + i]);
}

// tid0-only: spin until the 8 sub-counters (256B apart) sum to 128
__device__ __forceinline__ void poll128(int* base) {
  for (;;) {
    int s = 0;
#pragma unroll
    for (int j = 0; j < 8; j++)
      s += __hip_atomic_load(base + (j << 6), __ATOMIC_RELAXED, __HIP_MEMORY_SCOPE_AGENT);
    if (s >= 128) return;
    __builtin_amdgcn_s_sleep(1);
  }
}

// ---------------- persistent 2-layer LSTM, v3 ----------------
// 256 blocks x 512 threads, 1 block/CU. Blocks 0-127: layer0, 128-255: layer1.
// Both layers run the SAME step loop s=0..511; L1 trails via its waits.
// Weights resident in LDS in [kk][nrow][hi][16B] form: each wave's ds_read_b128
// set spans 1024 contiguous bytes -> ZERO bank conflicts.
// h via write-once history (plain cached loads, packed sc1 stores).
// Register pipeline: xa[16] = first half of NEXT step's dependency-free operand
// (L0: x, L1: h0), prefetched mid-step under the wait shadow; remaining
// fragments use 16-deep batched loads (ha[16]) for full MLP.
// Waits: L0@s: cnt0[s-1]. L1@s: cnt1[s-1] + cnt0[s+1] (prefetch gate, 2-slack).
__global__ __launch_bounds__(512) void lstm_persist(
    const unsigned short* __restrict__ W0s, const unsigned short* __restrict__ W1s,
    const float* __restrict__ b0, const float* __restrict__ b1,
    const unsigned short* __restrict__ xbf,
    unsigned short* h0hist, unsigned short* h1hist,
    const float* __restrict__ c0in, float* out, int* cnt)
{
  __shared__ short8 wlds[8192];   // 128 KB: [kk 0..63][nrow 0..31][hi 0..3]
  const int tid = threadIdx.x;
  const int bid = blockIdx.x;
  const int layer = bid >> 7;
  const int g = bid & 127;

  const unsigned short* Ws = layer ? W1s : W0s;
  const float* bias = layer ? b1 : b0;
  int* const cnt0 = cnt;                  // cnt0[s], stride 512 ints
  int* const cnt1 = cnt + (530 << 9);     // cnt1[s], stride 512 ints

  // ---- stage weight slice once: linear 128KB copy ----
  {
    const short8* wsrc = (const short8*)(Ws + ((size_t)g << 16));
#pragma unroll
    for (int it = 0; it < 16; it++)
      wlds[tid + (it << 9)] = wsrc[tid + (it << 9)];
  }

  // ---- wave / lane mapping ----
  const int lane = tid & 63;
  const int w  = tid >> 6;        // 0..7
  const int mt = w & 3;           // m-tile (batch)
  const int nt = w >> 2;          // n-tile 0..1
  const int m0 = mt << 4;
  const int n  = lane & 15;
  const int hi = lane >> 4;
  const int jl = n & 3;
  const int jg = (g << 3) + (nt << 2) + jl;    // h column 0..1023
  const int nrow = (nt << 4) + n;              // weight row in slice
  const short8* bbase = wlds + ((nrow << 2) + hi);   // + kk*128 per fragment
  const int rowoff = ((m0 + n) << 10) + (hi << 3);   // A-row base (elements)

  // ---- c state in registers (lanes n<4 hold 4 values each) ----
  float creg[4];
  float bi = 0.f, bfv = 0.f, bgv = 0.f, bov = 0.f;
  if (n < 4) {
    bi  = bias[jg];
    bfv = bias[1024 + jg];
    bgv = bias[2048 + jg];
    bov = bias[3072 + jg];
#pragma unroll
    for (int r = 0; r < 4; r++) {
      int m = m0 + (hi << 2) + r;
      creg[r] = c0in[(size_t)layer * BH + (m << 10) + jg];
    }
  }
  __syncthreads();

  // ---- prologue: gate + preload xa (first 16 fragments of step-0 operand A0) ----
  if (layer == 1) {
    if (tid == 0) poll128(cnt0);     // h0hist[1] complete
    __syncthreads();
  }
  short8 xa[16];
  {
    const unsigned short* arowA = ((layer == 0) ? xbf : h0hist + (size_t)BH) + rowoff;
#pragma unroll
    for (int j = 0; j < 16; j++) xa[j] = *(const short8*)(arowA + (j << 5));
  }

  for (int s = 0; s < TT; s++) {
    // ---------- PHASE A: dependency-free operand x first K-half ----------
    const unsigned short* inA = ((layer == 0) ? xbf + (size_t)s * BH
                                              : h0hist + (size_t)(s + 1) * BH) + rowoff;
    short8 ha[16];
#pragma unroll
    for (int j = 0; j < 16; j++) ha[j] = *(const short8*)(inA + ((16 + j) << 5));
    f32x4 acc = {0.0f, 0.0f, 0.0f, 0.0f};
#pragma unroll
    for (int j = 0; j < 16; j++)
      acc = __builtin_amdgcn_mfma_f32_16x16x32_bf16(xa[j], bbase[j << 7], acc, 0, 0, 0);
#pragma unroll
    for (int j = 0; j < 16; j++)
      acc = __builtin_amdgcn_mfma_f32_16x16x32_bf16(ha[j], bbase[(16 + j) << 7], acc, 0, 0, 0);

    // ---------- waits (tid0 single-line polls) ----------
    if (tid == 0) {
      if (layer == 0) {
        if (s >= 1) poll128(cnt0 + ((size_t)(s - 1) << 9));
      } else {
        if (s >= 1) poll128(cnt1 + ((size_t)(s - 1) << 9));
        if (s + 1 < TT) poll128(cnt0 + ((size_t)(s + 1) << 9));  // prefetch gate
      }
    }
    __syncthreads();

    // ---------- PHASE B: own-layer h second K-half (16-deep rolling) ----------
    const unsigned short* inB = ((layer == 0) ? h0hist + (size_t)s * BH
                                              : h1hist + (size_t)s * BH) + rowoff;
#pragma unroll
    for (int j = 0; j < 16; j++) ha[j] = *(const short8*)(inB + (j << 5));

    // prefetch next step's first-half operand into xa (hidden under phase B)
    if (s + 1 < TT) {
      const unsigned short* inAn = ((layer == 0) ? xbf + (size_t)(s + 1) * BH
                                                 : h0hist + (size_t)(s + 2) * BH) + rowoff;
#pragma unroll
      for (int j = 0; j < 16; j++) xa[j] = *(const short8*)(inAn + (j << 5));
    }

#pragma unroll
    for (int j = 0; j < 16; j++) {
      acc = __builtin_amdgcn_mfma_f32_16x16x32_bf16(ha[j], bbase[(32 + j) << 7], acc, 0, 0, 0);
      ha[j] = *(const short8*)(inB + ((16 + j) << 5));
    }
#pragma unroll
    for (int j = 0; j < 16; j++)
      acc = __builtin_amdgcn_mfma_f32_16x16x32_bf16(ha[j], bbase[(48 + j) << 7], acc, 0, 0, 0);

    // ---------- epilogue: gates, state update, h/out stores ----------
    unsigned short* hb = ((layer == 0) ? h0hist : h1hist) + (size_t)(s + 1) * BH;
    unsigned int* hb32 = (unsigned int*)hb;
    float* hf = nullptr;
    if (layer == 1) hf = out + (size_t)s * BH;              // hlast[s]
    else if (s == TT - 1) hf = out + (size_t)TT * BH;       // final h, layer 0

    const int src = (lane & 48) | jl;
#pragma unroll
    for (int r = 0; r < 4; r++) {
      float vi = __shfl(acc[r], src,      64);
      float vf = __shfl(acc[r], src | 4,  64);
      float vg = __shfl(acc[r], src | 8,  64);
      float vo = __shfl(acc[r], src | 12, 64);
      float hn = 0.f;
      int m = m0 + (hi << 2) + r;
      int idx = (m << 10) + jg;
      if (n < 4) {
        float ig = fsig(vi + bi);
        float fg = fsig(vf + bfv);
        float gg = ftanhf(vg + bgv);
        float og = fsig(vo + bov);
        float cn = ig * gg + fg * creg[r];
        hn = og * ftanhf(cn);
        creg[r] = cn;
        if (layer == 1 && s == TT - 1) {
          out[(size_t)TT * BH + BH + idx] = hn;        // final h, layer 1
          out[(size_t)TT * BH + 3 * BH + idx] = cn;    // final c, layer 1
        }
        if (layer == 0 && s == TT - 1) {
          out[(size_t)TT * BH + 2 * BH + idx] = cn;    // final c, layer 0
        }
      }
      float hn2 = __shfl(hn, lane + 1, 64);
      if (n < 4 && (n & 1) == 0) {
        unsigned int pack = (unsigned int)f2bf(hn) | ((unsigned int)f2bf(hn2) << 16);
        __hip_atomic_store(hb32 + (idx >> 1), pack, __ATOMIC_RELAXED, __HIP_MEMORY_SCOPE_AGENT);
        if (hf) *(float2*)(hf + idx) = make_float2(hn, hn2);
      }
    }

    // ---------- publish: drain stores (vmcnt0 at barrier), then 1 atomicAdd ----------
    __syncthreads();
    if (tid == 0) {
      int* c = (layer == 0) ? cnt0 : cnt1;
      atomicAdd(c + ((size_t)s << 9) + ((g & 7) << 6), 1);
    }
  }
}

extern "C" void kernel_launch(void* const* d_in, const int* in_sizes, int n_in,
                              void* d_out, int out_size, void* d_ws, size_t ws_size,
                              hipStream_t stream) {
  (void)in_sizes; (void)n_in; (void)out_size; (void)ws_size;
  const float* x    = (const float*)d_in[0];
  const float* h0in = (const float*)d_in[1];
  const float* c0in = (const float*)d_in[2];
  const float* W0   = (const float*)d_in[3];
  const float* b0   = (const float*)d_in[4];
  const float* W1   = (const float*)d_in[5];
  const float* b1   = (const float*)d_in[6];
  float* out = (float*)d_out;

  char* ws = (char*)d_ws;
  const size_t HIST = (size_t)(TT + 1) * BH * sizeof(unsigned short);  // 67,239,936 B
  unsigned short* Xbf    = (unsigned short*)(ws);                      // 64 MB
  unsigned short* W0s    = (unsigned short*)(ws + 67108864);           // 16 MB
  unsigned short* W1s    = (unsigned short*)(ws + 83886080);           // 16 MB
  unsigned short* h0hist = (unsigned short*)(ws + 100663296);          // 64.1 MB
  unsigned short* h1hist = (unsigned short*)(ws + 100663296 + HIST);   // 64.1 MB
  int* cnt               = (int*)(ws + 100663296 + 2 * HIST);          // ~2.2 MB

  const size_t CNT_BYTES = (size_t)(530 + TT) * 512 * sizeof(int);
  hipMemsetAsync(cnt, 0, CNT_BYTES, stream);
  cvt_x_kernel<<<2048, 256, 0, stream>>>(x, Xbf);
  cvt_w_kernel<<<4096, 256, 0, stream>>>(W0, W0s);
  cvt_w_kernel<<<4096, 256, 0, stream>>>(W1, W1s);
  init_state_kernel<<<256, 256, 0, stream>>>(h0in, h0hist, h1hist);

  lstm_persist<<<256, 512, 0, stream>>>(W0s, W1s, b0, b1, Xbf,
                                        h0hist, h1hist, c0in, out, cnt);
}